// Round 6
// baseline (592.445 us; speedup 1.0000x reference)
//
#include <hip/hip_runtime.h>
#include <hip/hip_bf16.h>
#include <cstdint>

// GAT forward, restructured:
//   softmax rows of (a_src[i] + a_dst[j]) == softmax of a_dst[j]  (row const cancels)
//   out = relu( ((A|I) @ (w*h)) / ((A|I) @ w) ),  w_j = exp(a_dst[j] - max)
// k_big v2b: wave-independent, ZERO-LDS, ZERO-barrier streaming MFMA kernel.
// k_h v2: 64x64 tile, 512 blocks (2/CU) -> latency hiding (was 1 wave/SIMD, ~300us).

typedef float  f32x4 __attribute__((ext_vector_type(4)));
typedef int    i32x4 __attribute__((ext_vector_type(4)));
typedef unsigned short u16x8 __attribute__((ext_vector_type(8)));
typedef __bf16 bf16x8 __attribute__((ext_vector_type(8)));

#define N_NODES 8192
#define F_IN    512
#define F_OUT   256
#define NC      272      // 256 h-cols + 1 denom col + 15 zero pad
#define SPLITK  4
#define KSPAN   2048
#define NSTEP   64       // KSPAN / 32

// Bt fragment-order layout: element (k, col) -> [ (k>>3)*NC + col ]*8 + (k&7)

#define V_OFF    0                    // 512 f32
#define SCAL_OFF 512                  // [0]=bias.phi_dst, [1]=global max
#define ADST_OFF 1024                 // 8192 f32
#define WV_OFF   (ADST_OFF + 8192)    // 8192 f32
#define BT_BYTE_OFF  ((WV_OFF + 8192) * 4)                      // 69632
#define PART_BYTE_OFF (BT_BYTE_OFF + (size_t)(N_NODES/8) * NC * 8 * 2)  // + 4456448

__device__ __forceinline__ unsigned short f2bf(float f) {
  unsigned u = __builtin_bit_cast(unsigned, f);
  unsigned r = (u + 0x7FFFu + ((u >> 16) & 1u)) >> 16;
  return (unsigned short)r;
}

// ---------------- k_prep: v = W @ phi_dst ; scal[0] = bias . phi_dst ----------------
__global__ __launch_bounds__(256) void k_prep(const float* __restrict__ W,
    const float* __restrict__ bias, const float* __restrict__ phi,
    float* __restrict__ v, float* __restrict__ scal) {
  __shared__ float sp[256];
  const int t = threadIdx.x;
  sp[t] = phi[256 + t];
  __syncthreads();
  const int k = blockIdx.x * 256 + t;
  const float* wr = W + (size_t)k * F_OUT;
  float acc = 0.f;
  #pragma unroll 4
  for (int c = 0; c < 256; c += 4) {
    f32x4 w4 = *(const f32x4*)(wr + c);
    f32x4 p4 = *(const f32x4*)(&sp[c]);
    acc += w4[0]*p4[0] + w4[1]*p4[1] + w4[2]*p4[2] + w4[3]*p4[3];
  }
  v[k] = acc;
  if (blockIdx.x == 0) {
    __shared__ float sd[256];
    sd[t] = bias[t] * sp[t];
    __syncthreads();
    for (int s = 128; s > 0; s >>= 1) { if (t < s) sd[t] += sd[t + s]; __syncthreads(); }
    if (t == 0) scal[0] = sd[0];
  }
}

// ---------------- k_adst: a_dst[j] = x[j,:] . v + bias_dot (f32, one wave per row) ----
__global__ __launch_bounds__(256) void k_adst(const float* __restrict__ x,
    const float* __restrict__ v, const float* __restrict__ scal,
    float* __restrict__ adst) {
  __shared__ float sv[512];
  const int t = threadIdx.x;
  sv[t] = v[t]; sv[t + 256] = v[t + 256];
  __syncthreads();
  const int lane = t & 63, wv = t >> 6;
  const int j = blockIdx.x * 4 + wv;
  const float* xr = x + (size_t)j * F_IN;
  f32x4 xa = *(const f32x4*)(xr + lane * 4);
  f32x4 xb = *(const f32x4*)(xr + 256 + lane * 4);
  f32x4 va = *(const f32x4*)(&sv[lane * 4]);
  f32x4 vb = *(const f32x4*)(&sv[256 + lane * 4]);
  float s = xa[0]*va[0] + xa[1]*va[1] + xa[2]*va[2] + xa[3]*va[3]
          + xb[0]*vb[0] + xb[1]*vb[1] + xb[2]*vb[2] + xb[3]*vb[3];
  #pragma unroll
  for (int off = 32; off > 0; off >>= 1) s += __shfl_down(s, off);
  if (lane == 0) adst[j] = s + scal[0];
}

// ---------------- k_max: global max of a_dst -> scal[1] ----------------
__global__ __launch_bounds__(256) void k_max(const float* __restrict__ adst,
    float* __restrict__ scal) {
  __shared__ float red[4];
  const int t = threadIdx.x;
  float m = -3.4e38f;
  #pragma unroll
  for (int i = 0; i < 32; ++i) m = fmaxf(m, adst[t + i * 256]);
  const int lane = t & 63;
  #pragma unroll
  for (int off = 32; off > 0; off >>= 1) m = fmaxf(m, __shfl_down(m, off));
  if (lane == 0) red[t >> 6] = m;
  __syncthreads();
  if (t == 0) scal[1] = fmaxf(fmaxf(red[0], red[1]), fmaxf(red[2], red[3]));
}

// ---------------- k_w: w = exp(a_dst - M); fills Bt cols 256..271 (denom + zero pad) --
__global__ __launch_bounds__(256) void k_w(const float* __restrict__ adst,
    const float* __restrict__ scal, float* __restrict__ wvec,
    unsigned short* __restrict__ Bt) {
  const int j8 = blockIdx.x * 256 + threadIdx.x;   // 0..1023
  const float M = scal[1];
  f32x4 a0 = *(const f32x4*)(adst + j8 * 8);
  f32x4 a1 = *(const f32x4*)(adst + j8 * 8 + 4);
  f32x4 w0, w1;
  #pragma unroll
  for (int q = 0; q < 4; ++q) { w0[q] = __expf(a0[q] - M); w1[q] = __expf(a1[q] - M); }
  *(f32x4*)(wvec + j8 * 8)     = w0;
  *(f32x4*)(wvec + j8 * 8 + 4) = w1;
  u16x8 o;
  #pragma unroll
  for (int q = 0; q < 4; ++q) { o[q] = f2bf(w0[q]); o[q + 4] = f2bf(w1[q]); }
  unsigned short* dst = Bt + ((size_t)j8 * NC + 256) * 8;
  *(u16x8*)dst = o;
  u16x8 z = {0, 0, 0, 0, 0, 0, 0, 0};
  #pragma unroll
  for (int cc = 1; cc < 16; ++cc) *(u16x8*)(dst + cc * 8) = z;
}

// ---------------- k_h v2: h = x@W + b (f32), Bt[(j>>3)*NC+c][j&7] = bf16(w_j*h) -------
// tile 64(j) x 64(c), 512 blocks (2/CU), thread = 8x2 micro (8 rows = one k-chunk)
__global__ __launch_bounds__(256, 2) void k_h(const float* __restrict__ x,
    const float* __restrict__ W, const float* __restrict__ bias,
    const float* __restrict__ wvec, unsigned short* __restrict__ Bt) {
  __shared__ float sx[64][32];
  __shared__ float sw[64][32];
  const int t = threadIdx.x;
  const int ty = t & 7, tx = t >> 3;            // 8 rows x (32 tx * 2 cols)
  const int j0 = blockIdx.x * 64, c0 = blockIdx.y * 64;
  float acc[8][2];
  #pragma unroll
  for (int r = 0; r < 8; ++r) { acc[r][0] = 0.f; acc[r][1] = 0.f; }

  for (int kt = 0; kt < F_IN / 32; ++kt) {
    const int k0 = kt * 32;
    __syncthreads();
    #pragma unroll
    for (int i = 0; i < 2; ++i) {               // x tile: 64 rows x 32 k (f32x4 loads)
      int n = t + i * 256, row = n >> 3, f4 = n & 7;
      f32x4 vv = *(const f32x4*)(x + (size_t)(j0 + row) * F_IN + k0 + f4 * 4);
      *(f32x4*)&sx[row][(f4 * 4) ^ (((row >> 3) & 7) << 2)] = vv;
    }
    #pragma unroll
    for (int i = 0; i < 8; ++i) {               // W tile transposed: 64 c x 32 k
      int n = t + i * 256, k = n >> 6, c = n & 63;
      sw[c][k ^ (((c >> 2) & 7) << 2)] = W[(size_t)(k0 + k) * F_OUT + c0 + c];
    }
    __syncthreads();
    #pragma unroll
    for (int kb4 = 0; kb4 < 8; ++kb4) {
      const int kb = kb4 * 4;
      f32x4 a4[8], b4[2];
      #pragma unroll
      for (int r = 0; r < 8; ++r) { int row = ty * 8 + r;
        a4[r] = *(const f32x4*)&sx[row][kb ^ (((row >> 3) & 7) << 2)]; }
      #pragma unroll
      for (int q = 0; q < 2; ++q) { int c = tx * 2 + q;
        b4[q] = *(const f32x4*)&sw[c][kb ^ (((c >> 2) & 7) << 2)]; }
      #pragma unroll
      for (int kk = 0; kk < 4; ++kk)
        #pragma unroll
        for (int r = 0; r < 8; ++r)
          #pragma unroll
          for (int q = 0; q < 2; ++q)
            acc[r][q] = fmaf(a4[r][kk], b4[q][kk], acc[r][q]);
    }
  }
  const int jr = j0 + ty * 8;                   // 8 consecutive rows = one k-chunk
  const int jq = (j0 >> 3) + ty;
  f32x4 w0 = *(const f32x4*)(wvec + jr);
  f32x4 w1 = *(const f32x4*)(wvec + jr + 4);
  #pragma unroll
  for (int q = 0; q < 2; ++q) {
    const int c = c0 + tx * 2 + q;
    const float bc = bias[c];
    u16x8 o;
    #pragma unroll
    for (int r = 0; r < 4; ++r) o[r]     = f2bf((acc[r][q]     + bc) * w0[r]);
    #pragma unroll
    for (int r = 0; r < 4; ++r) o[r + 4] = f2bf((acc[r + 4][q] + bc) * w1[r]);
    *(u16x8*)(Bt + ((size_t)jq * NC + c) * 8) = o;  // fragment-order layout
  }
}

// ---------------- k_big v2b: registers-only masked GEMM, 16 rows per wave -------------
__device__ __forceinline__ bf16x8 conv_mask(i32x4 lo, i32x4 hi, int d) {
  u16x8 v;
  #pragma unroll
  for (int e = 0; e < 4; ++e)
    v[e] = (lo[e] != 0 || d == e) ? (unsigned short)0x3F80 : (unsigned short)0;
  #pragma unroll
  for (int e = 0; e < 4; ++e)
    v[e + 4] = (hi[e] != 0 || d == e + 4) ? (unsigned short)0x3F80 : (unsigned short)0;
  return __builtin_bit_cast(bf16x8, v);
}

struct ARegs { i32x4 l, h; };

__device__ __forceinline__ void step_body(int T, bool pref,
    const int* __restrict__ a0p, const unsigned short* __restrict__ bp,
    ARegs& cur, ARegs& nxt, int d0b, f32x4 (&acc)[17]) {
  if (pref) {  // A(T+1): issue first so HBM stays fed while we compute
    nxt.l = *(const i32x4*)(a0p + (T + 1) * 32);
    nxt.h = *(const i32x4*)(a0p + (T + 1) * 32 + 4);
  }
  const unsigned short* bpt = bp + (size_t)T * (4 * NC * 8);
  bf16x8 b1[9];
  #pragma unroll
  for (int fb = 0; fb < 9; ++fb) b1[fb] = *(const bf16x8*)(bpt + fb * 128);
  bf16x8 af0 = conv_mask(cur.l, cur.h, d0b - T * 32);
  #pragma unroll
  for (int fb = 0; fb < 9; ++fb)
    acc[fb] = __builtin_amdgcn_mfma_f32_16x16x32_bf16(af0, b1[fb], acc[fb], 0, 0, 0);
  bf16x8 b2[8];   // second batch after first MFMAs caps live B-regs
  #pragma unroll
  for (int fb = 0; fb < 8; ++fb) b2[fb] = *(const bf16x8*)(bpt + (9 + fb) * 128);
  #pragma unroll
  for (int fb = 0; fb < 8; ++fb)
    acc[9 + fb] = __builtin_amdgcn_mfma_f32_16x16x32_bf16(af0, b2[fb], acc[9 + fb], 0, 0, 0);
}

__global__ __launch_bounds__(256, 2) void k_big(const int* __restrict__ adj,
    const unsigned short* __restrict__ Bt, float* __restrict__ part) {
  const int tid = threadIdx.x;
  const int gw = blockIdx.x * 4 + (tid >> 6);   // global wave id, 0..2047
  const int split = gw >> 9;                    // 0..3 (uniform within a block)
  const int strip = gw & 511;                   // 0..511, 16 rows each
  const int lane = tid & 63;
  const int l15 = lane & 15;
  const int kq  = lane >> 4;
  const int m0 = strip * 16;
  const int kbase = split * KSPAN;

  const int row0 = m0 + l15;
  const int* a0p = adj + (size_t)row0 * N_NODES + kbase + kq * 8;
  const unsigned short* bp = Bt + ((size_t)((kbase >> 3) + kq) * NC + l15) * 8;
  const int d0b = row0 - kbase - kq * 8;        // diag e-index at T=0

  f32x4 acc[17];
  #pragma unroll
  for (int b = 0; b < 17; ++b) acc[b] = f32x4{0.f, 0.f, 0.f, 0.f};

  ARegs Ac, An;
  Ac.l = *(const i32x4*)(a0p);
  Ac.h = *(const i32x4*)(a0p + 4);

  for (int t2 = 0; t2 < 31; ++t2) {
    step_body(2 * t2,     true, a0p, bp, Ac, An, d0b, acc);
    step_body(2 * t2 + 1, true, a0p, bp, An, Ac, d0b, acc);
  }
  step_body(62, true,  a0p, bp, Ac, An, d0b, acc);
  step_body(63, false, a0p, bp, An, Ac, d0b, acc);

  // C/D layout: col = lane&15, row = (lane>>4)*4 + reg  [verified m89]
  float* pr = part + ((size_t)split * N_NODES + m0) * NC;
  #pragma unroll
  for (int fb = 0; fb < 17; ++fb) {
    const int col = fb * 16 + l15;
    #pragma unroll
    for (int r = 0; r < 4; ++r) {
      const int row = kq * 4 + r;
      if (fb < 16) pr[(size_t)row * NC + col] = acc[fb][r];
      else if (l15 == 0) pr[(size_t)row * NC + 256] = acc[fb][r];
    }
  }
}

// ---------------- k_fin: out = relu( sum_s num / sum_s den ) ----------------
__global__ __launch_bounds__(256) void k_fin(const float* __restrict__ part,
    float* __restrict__ out) {
  const int i = blockIdx.x, c = threadIdx.x;
  const size_t S = (size_t)N_NODES * NC;
  const float* p = part + (size_t)i * NC;
  float num = 0.f, den = 0.f;
  #pragma unroll
  for (int s = 0; s < SPLITK; ++s) {
    num += p[(size_t)s * S + c];
    den += p[(size_t)s * S + 256];
  }
  out[(size_t)i * F_OUT + c] = fmaxf(num / den, 0.f);
}

extern "C" void kernel_launch(void* const* d_in, const int* in_sizes, int n_in,
                              void* d_out, int out_size, void* d_ws, size_t ws_size,
                              hipStream_t stream) {
  const int*   adj  = (const int*)d_in[0];
  const float* x    = (const float*)d_in[1];
  const float* W    = (const float*)d_in[2];
  const float* bias = (const float*)d_in[3];
  const float* phi  = (const float*)d_in[4];
  float* out = (float*)d_out;

  float* wsf  = (float*)d_ws;
  float* v    = wsf + V_OFF;
  float* scal = wsf + SCAL_OFF;
  float* adst = wsf + ADST_OFF;
  float* wvec = wsf + WV_OFF;
  unsigned short* Bt = (unsigned short*)((char*)d_ws + BT_BYTE_OFF);
  float* part = (float*)((char*)d_ws + PART_BYTE_OFF);

  k_prep<<<2, 256, 0, stream>>>(W, bias, phi, v, scal);
  k_adst<<<2048, 256, 0, stream>>>(x, v, scal, adst);
  k_max<<<1, 256, 0, stream>>>(adst, scal);
  k_w<<<4, 256, 0, stream>>>(adst, scal, wvec, Bt);
  k_h<<<dim3(128, 4), 256, 0, stream>>>(x, W, bias, wvec, Bt);
  k_big<<<512, 256, 0, stream>>>(adj, Bt, part);
  k_fin<<<8192, 256, 0, stream>>>(part, out);
}

// Round 8
// 502.705 us; speedup vs baseline: 1.1785x; 1.1785x over previous
//
#include <hip/hip_runtime.h>
#include <hip/hip_bf16.h>
#include <cstdint>

// GAT forward, restructured:
//   softmax rows of (a_src[i] + a_dst[j]) == softmax of a_dst[j]  (row const cancels)
//   out = relu( ((A|I) @ (w*h)) / ((A|I) @ w) ),  w_j = exp(a_dst[j] - max)
// k_big v3: LDS-staged (m97 structure) with CONTIGUOUS gload_lds sources:
//   - Bt fragment-order => per-step B tile is ONE contiguous 17408B region
//   - A staged via gload_lds with pre-swizzled source (linear dest, swizzled read)
//   - one __syncthreads per 32-k step; staged loads age a full step before the drain

typedef float  f32x4 __attribute__((ext_vector_type(4)));
typedef int    i32x4 __attribute__((ext_vector_type(4)));
typedef unsigned short u16x8 __attribute__((ext_vector_type(8)));
typedef __bf16 bf16x8 __attribute__((ext_vector_type(8)));

#define N_NODES 8192
#define F_IN    512
#define F_OUT   256
#define NC      272      // 256 h-cols + 1 denom col + 15 zero pad
#define SPLITK  4
#define KSPAN   2048
#define NSTEP   64       // KSPAN / 32
#define STEP_B  17408    // 4 * NC * 16 bytes per 32-k step of Bt

// Bt fragment-order layout: element (k, col) -> [ (k>>3)*NC + col ]*8 + (k&7)

#define V_OFF    0                    // 512 f32
#define SCAL_OFF 512                  // [0]=bias.phi_dst, [1]=global max
#define ADST_OFF 1024                 // 8192 f32
#define WV_OFF   (ADST_OFF + 8192)    // 8192 f32
#define BT_BYTE_OFF  ((WV_OFF + 8192) * 4)                      // 69632
#define PART_BYTE_OFF (BT_BYTE_OFF + (size_t)(N_NODES/8) * NC * 8 * 2)  // + 4456448

__device__ __forceinline__ unsigned short f2bf(float f) {
  unsigned u = __builtin_bit_cast(unsigned, f);
  unsigned r = (u + 0x7FFFu + ((u >> 16) & 1u)) >> 16;
  return (unsigned short)r;
}

__device__ __forceinline__ void gload_lds16(const void* g, void* l) {
  auto gp = (const __attribute__((address_space(1))) unsigned int*)(uintptr_t)g;
  auto lp = (__attribute__((address_space(3))) unsigned int*)(uintptr_t)l;
  __builtin_amdgcn_global_load_lds(gp, lp, 16, 0, 0);
}

// ---------------- k_prep: v = W @ phi_dst ; scal[0] = bias . phi_dst ----------------
__global__ __launch_bounds__(256) void k_prep(const float* __restrict__ W,
    const float* __restrict__ bias, const float* __restrict__ phi,
    float* __restrict__ v, float* __restrict__ scal) {
  __shared__ float sp[256];
  const int t = threadIdx.x;
  sp[t] = phi[256 + t];
  __syncthreads();
  const int k = blockIdx.x * 256 + t;
  const float* wr = W + (size_t)k * F_OUT;
  float acc = 0.f;
  #pragma unroll 4
  for (int c = 0; c < 256; c += 4) {
    f32x4 w4 = *(const f32x4*)(wr + c);
    f32x4 p4 = *(const f32x4*)(&sp[c]);
    acc += w4[0]*p4[0] + w4[1]*p4[1] + w4[2]*p4[2] + w4[3]*p4[3];
  }
  v[k] = acc;
  if (blockIdx.x == 0) {
    __shared__ float sd[256];
    sd[t] = bias[t] * sp[t];
    __syncthreads();
    for (int s = 128; s > 0; s >>= 1) { if (t < s) sd[t] += sd[t + s]; __syncthreads(); }
    if (t == 0) scal[0] = sd[0];
  }
}

// ---------------- k_adst: a_dst[j] = x[j,:] . v + bias_dot (f32, one wave per row) ----
__global__ __launch_bounds__(256) void k_adst(const float* __restrict__ x,
    const float* __restrict__ v, const float* __restrict__ scal,
    float* __restrict__ adst) {
  __shared__ float sv[512];
  const int t = threadIdx.x;
  sv[t] = v[t]; sv[t + 256] = v[t + 256];
  __syncthreads();
  const int lane = t & 63, wv = t >> 6;
  const int j = blockIdx.x * 4 + wv;
  const float* xr = x + (size_t)j * F_IN;
  f32x4 xa = *(const f32x4*)(xr + lane * 4);
  f32x4 xb = *(const f32x4*)(xr + 256 + lane * 4);
  f32x4 va = *(const f32x4*)(&sv[lane * 4]);
  f32x4 vb = *(const f32x4*)(&sv[256 + lane * 4]);
  float s = xa[0]*va[0] + xa[1]*va[1] + xa[2]*va[2] + xa[3]*va[3]
          + xb[0]*vb[0] + xb[1]*vb[1] + xb[2]*vb[2] + xb[3]*vb[3];
  #pragma unroll
  for (int off = 32; off > 0; off >>= 1) s += __shfl_down(s, off);
  if (lane == 0) adst[j] = s + scal[0];
}

// ---------------- k_max: global max of a_dst -> scal[1] ----------------
__global__ __launch_bounds__(256) void k_max(const float* __restrict__ adst,
    float* __restrict__ scal) {
  __shared__ float red[4];
  const int t = threadIdx.x;
  float m = -3.4e38f;
  #pragma unroll
  for (int i = 0; i < 32; ++i) m = fmaxf(m, adst[t + i * 256]);
  const int lane = t & 63;
  #pragma unroll
  for (int off = 32; off > 0; off >>= 1) m = fmaxf(m, __shfl_down(m, off));
  if (lane == 0) red[t >> 6] = m;
  __syncthreads();
  if (t == 0) scal[1] = fmaxf(fmaxf(red[0], red[1]), fmaxf(red[2], red[3]));
}

// ---------------- k_w: w = exp(a_dst - M); fills Bt cols 256..271 (denom + zero pad) --
__global__ __launch_bounds__(256) void k_w(const float* __restrict__ adst,
    const float* __restrict__ scal, float* __restrict__ wvec,
    unsigned short* __restrict__ Bt) {
  const int j8 = blockIdx.x * 256 + threadIdx.x;   // 0..1023
  const float M = scal[1];
  f32x4 a0 = *(const f32x4*)(adst + j8 * 8);
  f32x4 a1 = *(const f32x4*)(adst + j8 * 8 + 4);
  f32x4 w0, w1;
  #pragma unroll
  for (int q = 0; q < 4; ++q) { w0[q] = __expf(a0[q] - M); w1[q] = __expf(a1[q] - M); }
  *(f32x4*)(wvec + j8 * 8)     = w0;
  *(f32x4*)(wvec + j8 * 8 + 4) = w1;
  u16x8 o;
  #pragma unroll
  for (int q = 0; q < 4; ++q) { o[q] = f2bf(w0[q]); o[q + 4] = f2bf(w1[q]); }
  unsigned short* dst = Bt + ((size_t)j8 * NC + 256) * 8;
  *(u16x8*)dst = o;
  u16x8 z = {0, 0, 0, 0, 0, 0, 0, 0};
  #pragma unroll
  for (int cc = 1; cc < 16; ++cc) *(u16x8*)(dst + cc * 8) = z;
}

// ---------------- k_h v2: h = x@W + b (f32), Bt[(j>>3)*NC+c][j&7] = bf16(w_j*h) -------
// tile 64(j) x 64(c), 512 blocks (2/CU), thread = 8x2 micro (8 rows = one k-chunk)
__global__ __launch_bounds__(256, 2) void k_h(const float* __restrict__ x,
    const float* __restrict__ W, const float* __restrict__ bias,
    const float* __restrict__ wvec, unsigned short* __restrict__ Bt) {
  __shared__ float sx[64][32];
  __shared__ float sw[64][32];
  const int t = threadIdx.x;
  const int ty = t & 7, tx = t >> 3;            // 8 rows x (32 tx * 2 cols)
  const int j0 = blockIdx.x * 64, c0 = blockIdx.y * 64;
  float acc[8][2];
  #pragma unroll
  for (int r = 0; r < 8; ++r) { acc[r][0] = 0.f; acc[r][1] = 0.f; }

  for (int kt = 0; kt < F_IN / 32; ++kt) {
    const int k0 = kt * 32;
    __syncthreads();
    #pragma unroll
    for (int i = 0; i < 2; ++i) {               // x tile: 64 rows x 32 k (f32x4 loads)
      int n = t + i * 256, row = n >> 3, f4 = n & 7;
      f32x4 vv = *(const f32x4*)(x + (size_t)(j0 + row) * F_IN + k0 + f4 * 4);
      *(f32x4*)&sx[row][(f4 * 4) ^ (((row >> 3) & 7) << 2)] = vv;
    }
    #pragma unroll
    for (int i = 0; i < 8; ++i) {               // W tile transposed: 64 c x 32 k
      int n = t + i * 256, k = n >> 6, c = n & 63;
      sw[c][k ^ (((c >> 2) & 7) << 2)] = W[(size_t)(k0 + k) * F_OUT + c0 + c];
    }
    __syncthreads();
    #pragma unroll
    for (int kb4 = 0; kb4 < 8; ++kb4) {
      const int kb = kb4 * 4;
      f32x4 a4[8], b4[2];
      #pragma unroll
      for (int r = 0; r < 8; ++r) { int row = ty * 8 + r;
        a4[r] = *(const f32x4*)&sx[row][kb ^ (((row >> 3) & 7) << 2)]; }
      #pragma unroll
      for (int q = 0; q < 2; ++q) { int c = tx * 2 + q;
        b4[q] = *(const f32x4*)&sw[c][kb ^ (((c >> 2) & 7) << 2)]; }
      #pragma unroll
      for (int kk = 0; kk < 4; ++kk)
        #pragma unroll
        for (int r = 0; r < 8; ++r)
          #pragma unroll
          for (int q = 0; q < 2; ++q)
            acc[r][q] = fmaf(a4[r][kk], b4[q][kk], acc[r][q]);
    }
  }
  const int jr = j0 + ty * 8;                   // 8 consecutive rows = one k-chunk
  const int jq = (j0 >> 3) + ty;
  f32x4 w0 = *(const f32x4*)(wvec + jr);
  f32x4 w1 = *(const f32x4*)(wvec + jr + 4);
  #pragma unroll
  for (int q = 0; q < 2; ++q) {
    const int c = c0 + tx * 2 + q;
    const float bc = bias[c];
    u16x8 o;
    #pragma unroll
    for (int r = 0; r < 4; ++r) o[r]     = f2bf((acc[r][q]     + bc) * w0[r]);
    #pragma unroll
    for (int r = 0; r < 4; ++r) o[r + 4] = f2bf((acc[r + 4][q] + bc) * w1[r]);
    *(u16x8*)(Bt + ((size_t)jq * NC + c) * 8) = o;  // fragment-order layout
  }
}

// ---------------- k_big v3: LDS-staged masked GEMM, contiguous gload_lds --------------
__device__ __forceinline__ bf16x8 conv_mask(i32x4 lo, i32x4 hi, int d) {
  u16x8 v;
  #pragma unroll
  for (int e = 0; e < 4; ++e)
    v[e] = (lo[e] != 0 || d == e) ? (unsigned short)0x3F80 : (unsigned short)0;
  #pragma unroll
  for (int e = 0; e < 4; ++e)
    v[e + 4] = (hi[e] != 0 || d == e + 4) ? (unsigned short)0x3F80 : (unsigned short)0;
  return __builtin_bit_cast(bf16x8, v);
}

__global__ __launch_bounds__(256, 2) void k_big(const int* __restrict__ adj,
    const unsigned short* __restrict__ Bt, float* __restrict__ part) {
  __shared__ __align__(16) unsigned char sB[2][STEP_B];
  __shared__ __align__(16) unsigned char sA[2][8192];
  const int tid = threadIdx.x;
  const int bid = blockIdx.x;
  const int split = bid & 3;        // same-split blocks land on the same XCD (bid%8)
  const int mb = bid >> 2;          // 0..127
  const int wv = tid >> 6, lane = tid & 63;
  const int l15 = lane & 15, kq = lane >> 4;
  const int kbase = split * KSPAN;
  const int m0b = mb * 64;
  const int rowg = m0b + wv * 16 + l15;
  const int d0b = rowg - kbase - kq * 8;   // diag e-index at T=0

  const unsigned char* bsrc = (const unsigned char*)Bt + (size_t)(kbase >> 3) * (NC * 16);
  const unsigned char* asrc = (const unsigned char*)(adj) +
      ((size_t)m0b * N_NODES + kbase) * 4;

  // staging: all loop VMEM is global_load_lds (contiguous sources, linear LDS dest)
  auto stage = [&](int Tn, int nb) {
    const unsigned char* bs = bsrc + (size_t)Tn * STEP_B;
    #pragma unroll
    for (int i = 0; i < 4; ++i) {             // B: 1024 of 1088 16B chunks
      const int c = tid + 256 * i;
      gload_lds16(bs + c * 16, &sB[nb][c * 16]);
    }
    if (tid < 64) {                           // B: last 64 chunks (wave 0 only)
      const int c = 1024 + tid;
      gload_lds16(bs + c * 16, &sB[nb][c * 16]);
    }
    #pragma unroll
    for (int i = 0; i < 2; ++i) {             // A: 512 chunks, pre-swizzled source
      const int s = tid + 256 * i;
      const int r = s >> 3;
      const int kc = (s & 7) ^ (r & 7);       // inverse swizzle on SOURCE (rule 21)
      gload_lds16(asrc + (size_t)r * (N_NODES * 4) + (size_t)Tn * 128 + kc * 16,
                  &sA[nb][s * 16]);
    }
  };

  // swizzled LDS read addresses (row&7 == l15&7 since wave base is a multiple of 16)
  const int arow = wv * 16 + l15;
  const int aoff0 = arow * 128 + (((kq * 2 + 0) ^ (l15 & 7)) * 16);
  const int aoff1 = arow * 128 + (((kq * 2 + 1) ^ (l15 & 7)) * 16);
  const int boff = (kq * NC + l15) * 16;

  f32x4 acc[17];
  #pragma unroll
  for (int b = 0; b < 17; ++b) acc[b] = f32x4{0.f, 0.f, 0.f, 0.f};

  stage(0, 0);
  __syncthreads();

  int buf = 0;
  for (int T = 0; T < NSTEP; ++T) {
    if (T < NSTEP - 1) stage(T + 1, buf ^ 1);   // issue first: ages a full step
    i32x4 lo = *(const i32x4*)(sA[buf] + aoff0);
    i32x4 hi = *(const i32x4*)(sA[buf] + aoff1);
    bf16x8 af = conv_mask(lo, hi, d0b - T * 32);
    const unsigned char* lb = sB[buf] + boff;
    #pragma unroll
    for (int fb = 0; fb < 17; ++fb) {
      bf16x8 bb = *(const bf16x8*)(lb + fb * 256);
      acc[fb] = __builtin_amdgcn_mfma_f32_16x16x32_bf16(af, bb, acc[fb], 0, 0, 0);
    }
    __syncthreads();                             // vmcnt(0)+lgkmcnt(0)+barrier
    buf ^= 1;
  }

  // C/D layout: col = lane&15, row = (lane>>4)*4 + reg  [verified m89]
  float* pr = part + ((size_t)split * N_NODES + m0b + wv * 16) * NC;
  #pragma unroll
  for (int fb = 0; fb < 17; ++fb) {
    const int col = fb * 16 + l15;
    #pragma unroll
    for (int r = 0; r < 4; ++r) {
      const int row = kq * 4 + r;
      if (fb < 16) pr[(size_t)row * NC + col] = acc[fb][r];
      else if (l15 == 0) pr[(size_t)row * NC + 256] = acc[fb][r];
    }
  }
}

// ---------------- k_fin: out = relu( sum_s num / sum_s den ) ----------------
__global__ __launch_bounds__(256) void k_fin(const float* __restrict__ part,
    float* __restrict__ out) {
  const int i = blockIdx.x, c = threadIdx.x;
  const size_t S = (size_t)N_NODES * NC;
  const float* p = part + (size_t)i * NC;
  float num = 0.f, den = 0.f;
  #pragma unroll
  for (int s = 0; s < SPLITK; ++s) {
    num += p[(size_t)s * S + c];
    den += p[(size_t)s * S + 256];
  }
  out[(size_t)i * F_OUT + c] = fmaxf(num / den, 0.f);
}

extern "C" void kernel_launch(void* const* d_in, const int* in_sizes, int n_in,
                              void* d_out, int out_size, void* d_ws, size_t ws_size,
                              hipStream_t stream) {
  const int*   adj  = (const int*)d_in[0];
  const float* x    = (const float*)d_in[1];
  const float* W    = (const float*)d_in[2];
  const float* bias = (const float*)d_in[3];
  const float* phi  = (const float*)d_in[4];
  float* out = (float*)d_out;

  float* wsf  = (float*)d_ws;
  float* v    = wsf + V_OFF;
  float* scal = wsf + SCAL_OFF;
  float* adst = wsf + ADST_OFF;
  float* wvec = wsf + WV_OFF;
  unsigned short* Bt = (unsigned short*)((char*)d_ws + BT_BYTE_OFF);
  float* part = (float*)((char*)d_ws + PART_BYTE_OFF);

  k_prep<<<2, 256, 0, stream>>>(W, bias, phi, v, scal);
  k_adst<<<2048, 256, 0, stream>>>(x, v, scal, adst);
  k_max<<<1, 256, 0, stream>>>(adst, scal);
  k_w<<<4, 256, 0, stream>>>(adst, scal, wvec, Bt);
  k_h<<<dim3(128, 4), 256, 0, stream>>>(x, W, bias, wvec, Bt);
  k_big<<<512, 256, 0, stream>>>(adj, Bt, part);
  k_fin<<<8192, 256, 0, stream>>>(part, out);
}

// Round 9
// 485.048 us; speedup vs baseline: 1.2214x; 1.0364x over previous
//
#include <hip/hip_runtime.h>
#include <hip/hip_bf16.h>
#include <cstdint>

// GAT forward, restructured:
//   softmax rows of (a_src[i] + a_dst[j]) == softmax of a_dst[j]  (row const cancels)
//   out = relu( ((A|I) @ (w*h)) / ((A|I) @ w) ),  w_j = exp(a_dst[j] - max)
// k_big v4: fb-partitioned waves (B read once per block, LDS traffic -36%) +
//   counted-vmcnt triple-buffer pipeline (raw s_barrier, vmcnt(6), no per-step drain).

typedef float  f32x4 __attribute__((ext_vector_type(4)));
typedef int    i32x4 __attribute__((ext_vector_type(4)));
typedef unsigned short u16x8 __attribute__((ext_vector_type(8)));
typedef __bf16 bf16x8 __attribute__((ext_vector_type(8)));

#define N_NODES 8192
#define F_IN    512
#define F_OUT   256
#define NC      272      // 256 h-cols + 1 denom col + 15 zero pad
#define SPLITK  4
#define KSPAN   2048
#define NSTEP   64       // KSPAN / 32
#define STEP_B  17408    // 4 * NC * 16 bytes per 32-k step of Bt

// Bt fragment-order layout: element (k, col) -> [ (k>>3)*NC + col ]*8 + (k&7)

#define V_OFF    0                    // 512 f32
#define SCAL_OFF 512                  // [0]=bias.phi_dst, [1]=global max
#define ADST_OFF 1024                 // 8192 f32
#define WV_OFF   (ADST_OFF + 8192)    // 8192 f32
#define BT_BYTE_OFF  ((WV_OFF + 8192) * 4)                      // 69632
#define PART_BYTE_OFF (BT_BYTE_OFF + (size_t)(N_NODES/8) * NC * 8 * 2)  // + 4456448

__device__ __forceinline__ unsigned short f2bf(float f) {
  unsigned u = __builtin_bit_cast(unsigned, f);
  unsigned r = (u + 0x7FFFu + ((u >> 16) & 1u)) >> 16;
  return (unsigned short)r;
}

__device__ __forceinline__ void gload_lds16(const void* g, void* l) {
  auto gp = (const __attribute__((address_space(1))) unsigned int*)(uintptr_t)g;
  auto lp = (__attribute__((address_space(3))) unsigned int*)(uintptr_t)l;
  __builtin_amdgcn_global_load_lds(gp, lp, 16, 0, 0);
}

// ---------------- k_prep: v = W @ phi_dst ; scal[0] = bias . phi_dst ----------------
__global__ __launch_bounds__(256) void k_prep(const float* __restrict__ W,
    const float* __restrict__ bias, const float* __restrict__ phi,
    float* __restrict__ v, float* __restrict__ scal) {
  __shared__ float sp[256];
  const int t = threadIdx.x;
  sp[t] = phi[256 + t];
  __syncthreads();
  const int k = blockIdx.x * 256 + t;
  const float* wr = W + (size_t)k * F_OUT;
  float acc = 0.f;
  #pragma unroll 4
  for (int c = 0; c < 256; c += 4) {
    f32x4 w4 = *(const f32x4*)(wr + c);
    f32x4 p4 = *(const f32x4*)(&sp[c]);
    acc += w4[0]*p4[0] + w4[1]*p4[1] + w4[2]*p4[2] + w4[3]*p4[3];
  }
  v[k] = acc;
  if (blockIdx.x == 0) {
    __shared__ float sd[256];
    sd[t] = bias[t] * sp[t];
    __syncthreads();
    for (int s = 128; s > 0; s >>= 1) { if (t < s) sd[t] += sd[t + s]; __syncthreads(); }
    if (t == 0) scal[0] = sd[0];
  }
}

// ---------------- k_adst: a_dst[j] = x[j,:] . v + bias_dot (f32, one wave per row) ----
__global__ __launch_bounds__(256) void k_adst(const float* __restrict__ x,
    const float* __restrict__ v, const float* __restrict__ scal,
    float* __restrict__ adst) {
  __shared__ float sv[512];
  const int t = threadIdx.x;
  sv[t] = v[t]; sv[t + 256] = v[t + 256];
  __syncthreads();
  const int lane = t & 63, wv = t >> 6;
  const int j = blockIdx.x * 4 + wv;
  const float* xr = x + (size_t)j * F_IN;
  f32x4 xa = *(const f32x4*)(xr + lane * 4);
  f32x4 xb = *(const f32x4*)(xr + 256 + lane * 4);
  f32x4 va = *(const f32x4*)(&sv[lane * 4]);
  f32x4 vb = *(const f32x4*)(&sv[256 + lane * 4]);
  float s = xa[0]*va[0] + xa[1]*va[1] + xa[2]*va[2] + xa[3]*va[3]
          + xb[0]*vb[0] + xb[1]*vb[1] + xb[2]*vb[2] + xb[3]*vb[3];
  #pragma unroll
  for (int off = 32; off > 0; off >>= 1) s += __shfl_down(s, off);
  if (lane == 0) adst[j] = s + scal[0];
}

// ---------------- k_max: global max of a_dst -> scal[1] ----------------
__global__ __launch_bounds__(256) void k_max(const float* __restrict__ adst,
    float* __restrict__ scal) {
  __shared__ float red[4];
  const int t = threadIdx.x;
  float m = -3.4e38f;
  #pragma unroll
  for (int i = 0; i < 32; ++i) m = fmaxf(m, adst[t + i * 256]);
  const int lane = t & 63;
  #pragma unroll
  for (int off = 32; off > 0; off >>= 1) m = fmaxf(m, __shfl_down(m, off));
  if (lane == 0) red[t >> 6] = m;
  __syncthreads();
  if (t == 0) scal[1] = fmaxf(fmaxf(red[0], red[1]), fmaxf(red[2], red[3]));
}

// ---------------- k_w: w = exp(a_dst - M); fills Bt cols 256..271 (denom + zero pad) --
__global__ __launch_bounds__(256) void k_w(const float* __restrict__ adst,
    const float* __restrict__ scal, float* __restrict__ wvec,
    unsigned short* __restrict__ Bt) {
  const int j8 = blockIdx.x * 256 + threadIdx.x;   // 0..1023
  const float M = scal[1];
  f32x4 a0 = *(const f32x4*)(adst + j8 * 8);
  f32x4 a1 = *(const f32x4*)(adst + j8 * 8 + 4);
  f32x4 w0, w1;
  #pragma unroll
  for (int q = 0; q < 4; ++q) { w0[q] = __expf(a0[q] - M); w1[q] = __expf(a1[q] - M); }
  *(f32x4*)(wvec + j8 * 8)     = w0;
  *(f32x4*)(wvec + j8 * 8 + 4) = w1;
  u16x8 o;
  #pragma unroll
  for (int q = 0; q < 4; ++q) { o[q] = f2bf(w0[q]); o[q + 4] = f2bf(w1[q]); }
  unsigned short* dst = Bt + ((size_t)j8 * NC + 256) * 8;
  *(u16x8*)dst = o;
  u16x8 z = {0, 0, 0, 0, 0, 0, 0, 0};
  #pragma unroll
  for (int cc = 1; cc < 16; ++cc) *(u16x8*)(dst + cc * 8) = z;
}

// ---------------- k_h v2: h = x@W + b (f32), Bt[(j>>3)*NC+c][j&7] = bf16(w_j*h) -------
// tile 64(j) x 64(c), 512 blocks (2/CU), thread = 8x2 micro (8 rows = one k-chunk)
__global__ __launch_bounds__(256, 2) void k_h(const float* __restrict__ x,
    const float* __restrict__ W, const float* __restrict__ bias,
    const float* __restrict__ wvec, unsigned short* __restrict__ Bt) {
  __shared__ float sx[64][32];
  __shared__ float sw[64][32];
  const int t = threadIdx.x;
  const int ty = t & 7, tx = t >> 3;            // 8 rows x (32 tx * 2 cols)
  const int j0 = blockIdx.x * 64, c0 = blockIdx.y * 64;
  float acc[8][2];
  #pragma unroll
  for (int r = 0; r < 8; ++r) { acc[r][0] = 0.f; acc[r][1] = 0.f; }

  for (int kt = 0; kt < F_IN / 32; ++kt) {
    const int k0 = kt * 32;
    __syncthreads();
    #pragma unroll
    for (int i = 0; i < 2; ++i) {               // x tile: 64 rows x 32 k (f32x4 loads)
      int n = t + i * 256, row = n >> 3, f4 = n & 7;
      f32x4 vv = *(const f32x4*)(x + (size_t)(j0 + row) * F_IN + k0 + f4 * 4);
      *(f32x4*)&sx[row][(f4 * 4) ^ (((row >> 3) & 7) << 2)] = vv;
    }
    #pragma unroll
    for (int i = 0; i < 8; ++i) {               // W tile transposed: 64 c x 32 k
      int n = t + i * 256, k = n >> 6, c = n & 63;
      sw[c][k ^ (((c >> 2) & 7) << 2)] = W[(size_t)(k0 + k) * F_OUT + c0 + c];
    }
    __syncthreads();
    #pragma unroll
    for (int kb4 = 0; kb4 < 8; ++kb4) {
      const int kb = kb4 * 4;
      f32x4 a4[8], b4[2];
      #pragma unroll
      for (int r = 0; r < 8; ++r) { int row = ty * 8 + r;
        a4[r] = *(const f32x4*)&sx[row][kb ^ (((row >> 3) & 7) << 2)]; }
      #pragma unroll
      for (int q = 0; q < 2; ++q) { int c = tx * 2 + q;
        b4[q] = *(const f32x4*)&sw[c][kb ^ (((c >> 2) & 7) << 2)]; }
      #pragma unroll
      for (int kk = 0; kk < 4; ++kk)
        #pragma unroll
        for (int r = 0; r < 8; ++r)
          #pragma unroll
          for (int q = 0; q < 2; ++q)
            acc[r][q] = fmaf(a4[r][kk], b4[q][kk], acc[r][q]);
    }
  }
  const int jr = j0 + ty * 8;                   // 8 consecutive rows = one k-chunk
  const int jq = (j0 >> 3) + ty;
  f32x4 w0 = *(const f32x4*)(wvec + jr);
  f32x4 w1 = *(const f32x4*)(wvec + jr + 4);
  #pragma unroll
  for (int q = 0; q < 2; ++q) {
    const int c = c0 + tx * 2 + q;
    const float bc = bias[c];
    u16x8 o;
    #pragma unroll
    for (int r = 0; r < 4; ++r) o[r]     = f2bf((acc[r][q]     + bc) * w0[r]);
    #pragma unroll
    for (int r = 0; r < 4; ++r) o[r + 4] = f2bf((acc[r + 4][q] + bc) * w1[r]);
    *(u16x8*)(Bt + ((size_t)jq * NC + c) * 8) = o;  // fragment-order layout
  }
}

// ---------------- k_big v4: fb-partitioned waves + counted-vmcnt pipeline -------------
__device__ __forceinline__ bf16x8 conv_mask(i32x4 lo, i32x4 hi, int d) {
  u16x8 v;
  #pragma unroll
  for (int e = 0; e < 4; ++e)
    v[e] = (lo[e] != 0 || d == e) ? (unsigned short)0x3F80 : (unsigned short)0;
  #pragma unroll
  for (int e = 0; e < 4; ++e)
    v[e + 4] = (hi[e] != 0 || d == e + 4) ? (unsigned short)0x3F80 : (unsigned short)0;
  return __builtin_bit_cast(bf16x8, v);
}

// wave wv computes fb columns [fb0, fb0+NFB) for ALL 64 rows (4 row-groups).
// staging: 1600 chunks/step (B 1088 + A 512); thread t does 6 (wave0: 7) gload_lds.
// pipeline: triple buffer, stage(T+2) issued at step T, waited via vmcnt(6) at step T+2.
template<int NFB>
__device__ __forceinline__ void big_body(const int* __restrict__ adj,
    const unsigned short* __restrict__ Bt, float* __restrict__ part,
    unsigned char* sB0, unsigned char* sA0, int split, int mb, int tid, int fb0) {
  const int lane = tid & 63;
  const int l15 = lane & 15, kq = lane >> 4;
  const int kbase = split * KSPAN;
  const int m0b = mb * 64;

  const unsigned char* bsrc = (const unsigned char*)Bt + (size_t)(kbase >> 3) * (NC * 16);
  const unsigned char* asrc = (const unsigned char*)adj + ((size_t)m0b * N_NODES + kbase) * 4;

  int drg[4];
  int aoffs[4][2];
  #pragma unroll
  for (int rg = 0; rg < 4; ++rg) {
    const int arow = rg * 16 + l15;
    drg[rg] = (m0b + arow) - kbase - kq * 8;
    aoffs[rg][0] = arow * 128 + (((kq * 2 + 0) ^ (l15 & 7)) * 16);
    aoffs[rg][1] = arow * 128 + (((kq * 2 + 1) ^ (l15 & 7)) * 16);
  }
  const int boffbase = (kq * NC + fb0 * 16 + l15) * 16;

  f32x4 acc[4][NFB];
  #pragma unroll
  for (int rg = 0; rg < 4; ++rg)
    #pragma unroll
    for (int b = 0; b < NFB; ++b) acc[rg][b] = f32x4{0.f, 0.f, 0.f, 0.f};

  auto stage = [&](int Tn, int nb) {
    const unsigned char* bs = bsrc + (size_t)Tn * STEP_B;
    unsigned char* dB = sB0 + nb * STEP_B;
    unsigned char* dA = sA0 + nb * 8192;
    #pragma unroll
    for (int i = 0; i < 4; ++i) {             // chunks t..t+768: all B
      const int n = tid + (i << 8);
      gload_lds16(bs + (size_t)n * 16, dB + n * 16);
    }
    {                                          // chunk t+1024: B (t<64) or A
      const int n = tid + 1024;
      if (n < 1088) gload_lds16(bs + (size_t)n * 16, dB + n * 16);
      else {
        const int m = n - 1088, r = m >> 3, kc = (m & 7) ^ (r & 7);
        gload_lds16(asrc + (size_t)r * (N_NODES * 4) + (size_t)Tn * 128 + kc * 16,
                    dA + m * 16);
      }
    }
    {                                          // chunk t+1280: A (pre-swizzled source)
      const int m = tid + 192, r = m >> 3, kc = (m & 7) ^ (r & 7);
      gload_lds16(asrc + (size_t)r * (N_NODES * 4) + (size_t)Tn * 128 + kc * 16,
                  dA + m * 16);
    }
    if (tid < 64) {                            // chunk 1536+t: A (wave 0 only)
      const int m = tid + 448, r = m >> 3, kc = (m & 7) ^ (r & 7);
      gload_lds16(asrc + (size_t)r * (N_NODES * 4) + (size_t)Tn * 128 + kc * 16,
                  dA + m * 16);
    }
  };

  stage(0, 0);
  stage(1, 1);
  int cur = 0;
  for (int T = 0; T < NSTEP; ++T) {
    // stage(T) complete: uniform vmcnt(6) leaves only stage(T+1)'s 6 newest in flight
    if (T < NSTEP - 1) asm volatile("s_waitcnt vmcnt(6)" ::: "memory");
    else               asm volatile("s_waitcnt vmcnt(0)" ::: "memory");
    __builtin_amdgcn_sched_barrier(0);
    __builtin_amdgcn_s_barrier();              // all waves: stage(T) data visible
    if (T + 2 < NSTEP) {
      int nb = cur + 2; if (nb >= 3) nb -= 3;
      stage(T + 2, nb);                        // in flight across both barriers
    }
    const unsigned char* cA = sA0 + cur * 8192;
    const unsigned char* cB = sB0 + cur * STEP_B;
    bf16x8 af[4];
    #pragma unroll
    for (int rg = 0; rg < 4; ++rg) {
      i32x4 lo = *(const i32x4*)(cA + aoffs[rg][0]);
      i32x4 hi = *(const i32x4*)(cA + aoffs[rg][1]);
      af[rg] = conv_mask(lo, hi, drg[rg] - T * 32);
    }
    #pragma unroll
    for (int b = 0; b < NFB; ++b) {
      bf16x8 bb = *(const bf16x8*)(cB + boffbase + b * 256);
      #pragma unroll
      for (int rg = 0; rg < 4; ++rg)
        acc[rg][b] = __builtin_amdgcn_mfma_f32_16x16x32_bf16(af[rg], bb, acc[rg][b], 0, 0, 0);
    }
    __builtin_amdgcn_s_barrier();              // reads of buf[cur] done before overwrite
    cur = cur + 1; if (cur == 3) cur = 0;
  }

  // C/D layout: col = lane&15, row = (lane>>4)*4 + reg  [verified m89]
  float* pr = part + ((size_t)split * N_NODES + m0b) * NC;
  #pragma unroll
  for (int rg = 0; rg < 4; ++rg)
    #pragma unroll
    for (int b = 0; b < NFB; ++b) {
      const int fb = fb0 + b;
      #pragma unroll
      for (int r = 0; r < 4; ++r) {
        const int row = rg * 16 + kq * 4 + r;
        if (fb < 16) pr[(size_t)row * NC + fb * 16 + l15] = acc[rg][b][r];
        else if (l15 == 0) pr[(size_t)row * NC + 256] = acc[rg][b][r];
      }
    }
}

__global__ __launch_bounds__(256, 2) void k_big(const int* __restrict__ adj,
    const unsigned short* __restrict__ Bt, float* __restrict__ part) {
  __shared__ __align__(16) unsigned char sB[3][STEP_B];
  __shared__ __align__(16) unsigned char sA[3][8192];
  const int tid = threadIdx.x;
  const int bid = blockIdx.x;
  const int split = bid & 3;        // same-split blocks share B stream / XCD pair
  const int mb = bid >> 2;          // 0..127
  const int wv = tid >> 6;
  if (wv < 3) big_body<4>(adj, Bt, part, &sB[0][0], &sA[0][0], split, mb, tid, wv * 4);
  else        big_body<5>(adj, Bt, part, &sB[0][0], &sA[0][0], split, mb, tid, 12);
}

// ---------------- k_fin: out = relu( sum_s num / sum_s den ) ----------------
__global__ __launch_bounds__(256) void k_fin(const float* __restrict__ part,
    float* __restrict__ out) {
  const int i = blockIdx.x, c = threadIdx.x;
  const size_t S = (size_t)N_NODES * NC;
  const float* p = part + (size_t)i * NC;
  float num = 0.f, den = 0.f;
  #pragma unroll
  for (int s = 0; s < SPLITK; ++s) {
    num += p[(size_t)s * S + c];
    den += p[(size_t)s * S + 256];
  }
  out[(size_t)i * F_OUT + c] = fmaxf(num / den, 0.f);
}

extern "C" void kernel_launch(void* const* d_in, const int* in_sizes, int n_in,
                              void* d_out, int out_size, void* d_ws, size_t ws_size,
                              hipStream_t stream) {
  const int*   adj  = (const int*)d_in[0];
  const float* x    = (const float*)d_in[1];
  const float* W    = (const float*)d_in[2];
  const float* bias = (const float*)d_in[3];
  const float* phi  = (const float*)d_in[4];
  float* out = (float*)d_out;

  float* wsf  = (float*)d_ws;
  float* v    = wsf + V_OFF;
  float* scal = wsf + SCAL_OFF;
  float* adst = wsf + ADST_OFF;
  float* wvec = wsf + WV_OFF;
  unsigned short* Bt = (unsigned short*)((char*)d_ws + BT_BYTE_OFF);
  float* part = (float*)((char*)d_ws + PART_BYTE_OFF);

  k_prep<<<2, 256, 0, stream>>>(W, bias, phi, v, scal);
  k_adst<<<2048, 256, 0, stream>>>(x, v, scal, adst);
  k_max<<<1, 256, 0, stream>>>(adst, scal);
  k_w<<<4, 256, 0, stream>>>(adst, scal, wvec, Bt);
  k_h<<<dim3(128, 4), 256, 0, stream>>>(x, W, bias, wvec, Bt);
  k_big<<<512, 256, 0, stream>>>(adj, Bt, part);
  k_fin<<<8192, 256, 0, stream>>>(part, out);
}